// Round 2
// baseline (205.087 us; speedup 1.0000x reference)
//
#include <hip/hip_runtime.h>

// Problem constants (match reference setup_inputs)
#define TT 32
#define BB 16
#define VV 50000
#define LL 400
#define MAX_OOV 100
#define EV (VV + MAX_OOV)       // 50100 floats per row (divisible by 4)
#define EV4 (EV / 4)            // 12525 float4 slots
#define V4  (VV / 4)            // 12500 float4 slots
#define NTHREADS 512
#define FULL_ITERS (V4 / NTHREADS)   // 24 uniform iterations (24*512 = 12288)

// One block per (t,b) row. Phase 1: gated copy of vocab -> out (float4,
// coalesced) + zero the OOV pad. Phase 2 (after barrier, row still L2-hot):
// scatter-add the copy distribution into the same row.
__global__ __launch_bounds__(NTHREADS) void fdl_fused_kernel(
    const float* __restrict__ vocab,   // [T*B, V]
    const float* __restrict__ attn,    // [T*B, L]
    const float* __restrict__ pgen,    // [T*B]
    const int*   __restrict__ ids,     // [B, L]
    float* __restrict__ out)           // [T*B, EV]
{
    const int row = blockIdx.x;              // t*B + b  (512 rows)
    const int tid = threadIdx.x;
    const float p = pgen[row];

    const float4* __restrict__ v4 =
        reinterpret_cast<const float4*>(vocab + (size_t)row * VV);
    float4* __restrict__ o4 =
        reinterpret_cast<float4*>(out + (size_t)row * EV);

    // ---- Phase 1: gate + pad ----
    int i = tid;
    #pragma unroll 4
    for (int it = 0; it < FULL_ITERS; ++it, i += NTHREADS) {
        float4 v = v4[i];
        v.x *= p; v.y *= p; v.z *= p; v.w *= p;
        o4[i] = v;
    }
    // tail: slots 12288..12499 (212 slots, tid < 212)
    if (i < V4) {
        float4 v = v4[i];
        v.x *= p; v.y *= p; v.z *= p; v.w *= p;
        o4[i] = v;
    }
    // OOV pad: slots 12500..12524 (25 slots)
    if (tid < EV4 - V4) {
        o4[V4 + tid] = make_float4(0.f, 0.f, 0.f, 0.f);
    }

    // Make phase-1 writes visible (syncthreads drains vmcnt on gfx950),
    // then scatter into the still-L2-hot row.
    __syncthreads();

    // ---- Phase 2: scatter-add copy distribution ----
    const int b = row % BB;                         // wave-uniform per block
    const float q = 1.0f - p;
    float* __restrict__ orow = out + (size_t)row * EV;
    const float* __restrict__ arow = attn + (size_t)row * LL;
    const int* __restrict__ irow = ids + (size_t)b * LL;

    if (tid < LL) {                                  // 400 entries, tid 0..399
        atomicAdd(orow + irow[tid], q * arow[tid]);
    }
}

extern "C" void kernel_launch(void* const* d_in, const int* in_sizes, int n_in,
                              void* d_out, int out_size, void* d_ws, size_t ws_size,
                              hipStream_t stream) {
    const float* vocab = (const float*)d_in[0];   // [T,B,V]
    const float* attn  = (const float*)d_in[1];   // [T,B,L]
    const float* pgen  = (const float*)d_in[2];   // [T,B,1]
    const int*   ids   = (const int*)d_in[3];     // [B,L]
    float* out = (float*)d_out;                   // [T,B,EV]

    fdl_fused_kernel<<<TT * BB, NTHREADS, 0, stream>>>(vocab, attn, pgen, ids, out);
}